// Round 5
// baseline (209.033 us; speedup 1.0000x reference)
//
#include <hip/hip_runtime.h>
#include <math.h>

#define NSTEPS 18
#define NS 128      // N_CES*B
#define CHW 12288   // 3*64*64
#define HW 4096     // 64*64
#define NCLS 1000
#define WROWS 50    // LDS window rows per block (32 owned + 18 halo, clipped)
#define BUFF (3 * WROWS * 64)   // floats per buffer

struct StepC { float c_skip, c_out, c_in, inv_t, ce, two_dt, nc, pad; };
struct Steps { StepC s[NSTEPS]; float t0; };

typedef __attribute__((ext_vector_type(8))) short v8s;
typedef __attribute__((ext_vector_type(4))) float v4f;

__device__ __forceinline__ unsigned short f2bf(float f) {
    unsigned int u = __float_as_uint(f);
    unsigned int r = (u + 0x7FFFu + ((u >> 16) & 1u)) >> 16;   // RNE
    return (unsigned short)r;
}

// ---- Sampler: 2 blocks/sample, 16 lanes/row (conflict-free LDS), dbuf ----
// __launch_bounds__(832, 4): 4 waves/EU min -> 128-VGPR cap. Kernel needs ~104.
// (832,<none>) and (448,4)-with-64-VGPR both spilled catastrophically (R2/R4).
__global__ __launch_bounds__(832, 4)
void sampler_kernel(const float* __restrict__ x, const float* __restrict__ latents,
                    const float* __restrict__ noise, const float* __restrict__ Wn_g,
                    const float* __restrict__ bn_g, unsigned short* __restrict__ Aout, Steps S)
{
    __shared__ float xs[2 * BUFF];     // 76.8 KB double buffer
    __shared__ float Wn[81];
    __shared__ float bn[3];
    const int tid = threadIdx.x;
    const int n = blockIdx.x >> 1;
    const int q = blockIdx.x & 1;
    const int base = q << 5;             // first owned row (0 or 32)
    const int w0 = q ? 14 : 0;           // window start row

    if (tid < 81) Wn[tid] = Wn_g[tid];
    if (tid < 3)  bn[tid] = bn_g[tid];

    const int lr = tid >> 4;            // local row slot 0..51
    const int cg = tid & 15;            // col group
    const int col = cg << 2;
    const int gr = w0 + lr;             // global row
    const bool rowv = (lr < WROWS);

    const float t0 = S.t0;
    const float* lat = latents + (size_t)n * CHW;
    const float* xin = x + (size_t)(n & 63) * CHW;

    // own-row state in registers + stage buffer 0; preload mu = 2*x-1
    float xc[3][4], mu[3][4];
    if (rowv) {
        #pragma unroll
        for (int ci = 0; ci < 3; ++ci) {
            float4 v = *reinterpret_cast<const float4*>(lat + ci * HW + gr * 64 + col);
            v.x *= t0; v.y *= t0; v.z *= t0; v.w *= t0;
            xc[ci][0]=v.x; xc[ci][1]=v.y; xc[ci][2]=v.z; xc[ci][3]=v.w;
            *reinterpret_cast<float4*>(&xs[(ci * WROWS + lr) * 64 + col]) = v;
            float4 m = *reinterpret_cast<const float4*>(xin + ci * HW + gr * 64 + col);
            mu[ci][0] = 2.f*m.x - 1.f; mu[ci][1] = 2.f*m.y - 1.f;
            mu[ci][2] = 2.f*m.z - 1.f; mu[ci][3] = 2.f*m.w - 1.f;
        }
    }
    __syncthreads();

    int cur = 0;
    for (int step = 0; step < NSTEPS; ++step) {
        const StepC c = S.s[step];
        const int lo = base - 17 + step;
        const int hi = base + 49 - step;
        const bool active = rowv && (gr >= lo) && (gr < hi);

        if (active) {
            float acc[3][4];
            #pragma unroll
            for (int co = 0; co < 3; ++co)
                #pragma unroll
                for (int j = 0; j < 4; ++j) acc[co][j] = 0.f;

            #pragma unroll
            for (int ci = 0; ci < 3; ++ci) {
                float in0[6], in2[6], cen[6];
                // row gr-1 from LDS
                if (gr >= 1) {
                    float4 a = *reinterpret_cast<const float4*>(
                        &xs[cur * BUFF + (ci * WROWS + lr - 1) * 64 + col]);
                    in0[1]=a.x; in0[2]=a.y; in0[3]=a.z; in0[4]=a.w;
                    in0[0] = (cg > 0)  ? __shfl_up(a.w, 1)  : 0.f;
                    in0[5] = (cg < 15) ? __shfl_down(a.x, 1) : 0.f;
                } else {
                    #pragma unroll
                    for (int p = 0; p < 6; ++p) in0[p] = 0.f;
                }
                // row gr+1 from LDS
                if (gr + 1 < 64) {
                    float4 a = *reinterpret_cast<const float4*>(
                        &xs[cur * BUFF + (ci * WROWS + lr + 1) * 64 + col]);
                    in2[1]=a.x; in2[2]=a.y; in2[3]=a.z; in2[4]=a.w;
                    in2[0] = (cg > 0)  ? __shfl_up(a.w, 1)  : 0.f;
                    in2[5] = (cg < 15) ? __shfl_down(a.x, 1) : 0.f;
                } else {
                    #pragma unroll
                    for (int p = 0; p < 6; ++p) in2[p] = 0.f;
                }
                // own row from registers
                cen[0] = (cg > 0)  ? __shfl_up(xc[ci][3], 1)  : 0.f;
                cen[5] = (cg < 15) ? __shfl_down(xc[ci][0], 1) : 0.f;
                #pragma unroll
                for (int j = 0; j < 4; ++j) cen[j + 1] = xc[ci][j];

                #pragma unroll
                for (int co = 0; co < 3; ++co) {
                    const int wb = (co * 3 + ci) * 9;
                    #pragma unroll
                    for (int dw = 0; dw < 3; ++dw) {
                        const float w0t = Wn[wb + dw];
                        const float w1t = Wn[wb + 3 + dw];
                        const float w2t = Wn[wb + 6 + dw];
                        #pragma unroll
                        for (int j = 0; j < 4; ++j) {
                            acc[co][j] = fmaf(w0t, in0[j + dw],
                                         fmaf(w1t, cen[j + dw],
                                         fmaf(w2t, in2[j + dw], acc[co][j])));
                        }
                    }
                }
            }

            // EDM update
            const float* nz = noise + ((size_t)(step * NS + n)) * CHW;
            #pragma unroll
            for (int co = 0; co < 3; ++co) {
                float eps[4] = {0.f, 0.f, 0.f, 0.f};
                if (step < NSTEPS - 2) {
                    float4 e = *reinterpret_cast<const float4*>(nz + co * HW + gr * 64 + col);
                    eps[0]=e.x; eps[1]=e.y; eps[2]=e.z; eps[3]=e.w;
                }
                #pragma unroll
                for (int j = 0; j < 4; ++j) {
                    const float xv = xc[co][j];
                    const float f = fmaf(c.c_in, acc[co][j], bn[co]);
                    const float den = c.c_skip * xv + c.c_out * f;
                    const float dx = (den - xv) * c.inv_t + c.ce * (mu[co][j] - xv);
                    xc[co][j] = fmaf(c.two_dt, dx, fmaf(c.nc, eps[j], xv));
                }
            }
            // write new state to the other buffer
            #pragma unroll
            for (int co = 0; co < 3; ++co)
                *reinterpret_cast<float4*>(&xs[(cur ^ 1) * BUFF + (co * WROWS + lr) * 64 + col]) =
                    make_float4(xc[co][0], xc[co][1], xc[co][2], xc[co][3]);
        }
        __syncthreads();
        cur ^= 1;
    }

    // epilogue: xc holds final values for owned rows; write A=(x+1)/2 as bf16
    if (rowv && gr >= base && gr < base + 32) {
        unsigned short* Ao = Aout + (size_t)n * CHW;
        #pragma unroll
        for (int ci = 0; ci < 3; ++ci) {
            ushort4 o;
            o.x = f2bf((xc[ci][0] + 1.f) * 0.5f); o.y = f2bf((xc[ci][1] + 1.f) * 0.5f);
            o.z = f2bf((xc[ci][2] + 1.f) * 0.5f); o.w = f2bf((xc[ci][3] + 1.f) * 0.5f);
            *reinterpret_cast<ushort4*>(Ao + ci * HW + gr * 64 + col) = o;
        }
    }
}

// ---- GEMM: bf16 MFMA, A bf16 from ws, Wc f32 converted in-register, no LDS ----
__global__ __launch_bounds__(256)
void gemm_kernel(const unsigned short* __restrict__ Abf, const float* __restrict__ Wc,
                 float* __restrict__ part, int bkc)
{
    const int tid = threadIdx.x;
    const int wv = tid >> 6;
    const int lane = tid & 63;
    const int lrow = lane & 15;
    const int lk8 = (lane >> 4) << 3;
    const int ct = blockIdx.x & 15;
    const int kc = blockIdx.x >> 4;
    const int c0 = ct << 6;
    const int k0 = kc * bkc;

    v4f acc[2][4];
    #pragma unroll
    for (int rt = 0; rt < 2; ++rt)
        #pragma unroll
        for (int c4 = 0; c4 < 4; ++c4) acc[rt][c4] = (v4f)0.f;

    #pragma unroll 2
    for (int kk = 0; kk < bkc; kk += 32) {
        const int kb = k0 + kk + lk8;
        v8s a[2];
        #pragma unroll
        for (int rt = 0; rt < 2; ++rt)
            a[rt] = *reinterpret_cast<const v8s*>(Abf + (size_t)(wv * 32 + rt * 16 + lrow) * CHW + kb);
        v8s b[4];
        #pragma unroll
        for (int c4 = 0; c4 < 4; ++c4) {
            const int col = c0 + c4 * 16 + lrow;
            const bool cv = (col < NCLS);
            #pragma unroll
            for (int j = 0; j < 8; ++j) {
                const float f = cv ? Wc[(size_t)(kb + j) * NCLS + col] : 0.f;
                b[c4][j] = (short)f2bf(f);
            }
        }
        #pragma unroll
        for (int rt = 0; rt < 2; ++rt)
            #pragma unroll
            for (int c4 = 0; c4 < 4; ++c4)
                acc[rt][c4] = __builtin_amdgcn_mfma_f32_16x16x32_bf16(a[rt], b[c4], acc[rt][c4], 0, 0, 0);
    }

    float* pp = part + (size_t)kc * NS * NCLS;
    #pragma unroll
    for (int rt = 0; rt < 2; ++rt)
        #pragma unroll
        for (int c4 = 0; c4 < 4; ++c4) {
            const int col = c0 + c4 * 16 + lrow;
            if (col < NCLS) {
                #pragma unroll
                for (int r = 0; r < 4; ++r) {
                    const int row = wv * 32 + rt * 16 + (lane >> 4) * 4 + r;
                    pp[(size_t)row * NCLS + col] = acc[rt][c4][r];
                }
            }
        }
}

// ---- Reduce partials + bias + logsumexp over the 2 CEs ----
__global__ __launch_bounds__(256)
void lse_kernel(const float* __restrict__ part, const float* __restrict__ bcls,
                float* __restrict__ out, int ks)
{
    const int i = blockIdx.x * 256 + threadIdx.x;
    if (i >= 64 * NCLS) return;
    const int b = i / NCLS;
    const int k = i - b * NCLS;
    float l0 = bcls[k], l1 = bcls[k];
    for (int kc = 0; kc < ks; ++kc) {
        l0 += part[(size_t)kc * NS * NCLS + (size_t)b * NCLS + k];
        l1 += part[(size_t)kc * NS * NCLS + (size_t)(b + 64) * NCLS + k];
    }
    const float m = fmaxf(l0, l1);
    out[i] = m + logf(expf(l0 - m) + expf(l1 - m)) - 0.69314718055994530942f;
}

extern "C" void kernel_launch(void* const* d_in, const int* in_sizes, int n_in,
                              void* d_out, int out_size, void* d_ws, size_t ws_size,
                              hipStream_t stream) {
    const float* x       = (const float*)d_in[0];
    const float* latents = (const float*)d_in[1];
    const float* noise   = (const float*)d_in[2];
    const float* W_net   = (const float*)d_in[3];
    const float* b_net   = (const float*)d_in[4];
    const float* W_cls   = (const float*)d_in[5];
    const float* b_cls   = (const float*)d_in[6];
    float* out = (float*)d_out;

    unsigned short* Amat = (unsigned short*)d_ws;            // 128*12288 bf16
    const size_t amat_bytes = (size_t)NS * CHW * 2;
    float* part = (float*)((char*)d_ws + amat_bytes);

    // Karras sigma schedule in float64 (matches numpy), cast to f32
    Steps S;
    const double smin = pow(0.002, 1.0 / 7.0), smax = pow(80.0, 1.0 / 7.0);
    float tsf[NSTEPS + 1];
    for (int i = 0; i < NSTEPS; ++i) {
        double v = smax + (double)i / (double)(NSTEPS - 1) * (smin - smax);
        tsf[i] = (float)pow(v, 7.0);
    }
    tsf[NSTEPS] = 0.f;
    S.t0 = tsf[0];
    for (int i = 0; i < NSTEPS; ++i) {
        const float t = tsf[i], tn = tsf[i + 1];
        const float s2 = t * t, denom = s2 + 0.25f;
        StepC c;
        c.c_skip = 0.25f / denom;
        c.c_out  = t * 0.5f / sqrtf(denom);
        c.c_in   = 1.0f / sqrtf(denom);
        c.inv_t  = 1.0f / t;
        c.ce     = t / (0.04f + s2);
        const float dt = t - tn;
        c.two_dt = 2.f * dt;
        c.nc     = sqrtf(2.f * t * dt);
        c.pad    = 0.f;
        S.s[i] = c;
    }

    // K-split sized to workspace
    int KS = 32;
    while (KS > 1 && amat_bytes + (size_t)KS * NS * NCLS * 4 > ws_size) KS >>= 1;
    const int bkc = CHW / KS;

    sampler_kernel<<<NS * 2, 832, 0, stream>>>(x, latents, noise, W_net, b_net, Amat, S);
    gemm_kernel<<<16 * KS, 256, 0, stream>>>(Amat, W_cls, part, bkc);
    lse_kernel<<<(64 * NCLS + 255) / 256, 256, 0, stream>>>(part, b_cls, out, KS);
}

// Round 6
// 208.818 us; speedup vs baseline: 1.0010x; 1.0010x over previous
//
#include <hip/hip_runtime.h>
#include <math.h>

#define NSTEPS 18
#define NS 128      // N_CES*B
#define CHW 12288   // 3*64*64
#define HW 4096     // 64*64
#define NCLS 1000
#define WROWS 50    // LDS window rows per block (32 owned + 18 halo, clipped)
#define BUFF (3 * WROWS * 64)   // floats per buffer

struct StepC { float c_skip, c_out, c_in, inv_t, ce, two_dt, nc, pad; };
struct Steps { StepC s[NSTEPS]; float t0; };

typedef __attribute__((ext_vector_type(8))) short v8s;
typedef __attribute__((ext_vector_type(4))) float v4f;

__device__ __forceinline__ unsigned short f2bf(float f) {
    unsigned int u = __float_as_uint(f);
    unsigned int r = (u + 0x7FFFu + ((u >> 16) & 1u)) >> 16;   // RNE
    return (unsigned short)r;
}

// ---- Sampler: 2 blocks/sample, 16 lanes/row (conflict-free LDS), dbuf ----
// EMPIRICAL compiler model (R0-R5): VGPR cap = 256 / min_waves_per_EU,
// default min_waves = ceil(block_waves/4). 13-wave block => must pass 2
// to get the 128-VGPR cap this kernel needs (~104). (832,4)/(832,none)
// both capped at 64 and spilled 300MB to scratch.
__global__ __launch_bounds__(832, 2)
void sampler_kernel(const float* __restrict__ x, const float* __restrict__ latents,
                    const float* __restrict__ noise, const float* __restrict__ Wn_g,
                    const float* __restrict__ bn_g, unsigned short* __restrict__ Aout, Steps S)
{
    __shared__ float xs[2 * BUFF];     // 76.8 KB double buffer
    __shared__ float Wn[81];
    __shared__ float bn[3];
    const int tid = threadIdx.x;
    const int n = blockIdx.x >> 1;
    const int q = blockIdx.x & 1;
    const int base = q << 5;             // first owned row (0 or 32)
    const int w0 = q ? 14 : 0;           // window start row

    if (tid < 81) Wn[tid] = Wn_g[tid];
    if (tid < 3)  bn[tid] = bn_g[tid];

    const int lr = tid >> 4;            // local row slot 0..51
    const int cg = tid & 15;            // col group
    const int col = cg << 2;
    const int gr = w0 + lr;             // global row
    const bool rowv = (lr < WROWS);

    const float t0 = S.t0;
    const float* lat = latents + (size_t)n * CHW;
    const float* xin = x + (size_t)(n & 63) * CHW;

    // own-row state in registers + stage buffer 0; preload mu = 2*x-1
    float xc[3][4], mu[3][4];
    if (rowv) {
        #pragma unroll
        for (int ci = 0; ci < 3; ++ci) {
            float4 v = *reinterpret_cast<const float4*>(lat + ci * HW + gr * 64 + col);
            v.x *= t0; v.y *= t0; v.z *= t0; v.w *= t0;
            xc[ci][0]=v.x; xc[ci][1]=v.y; xc[ci][2]=v.z; xc[ci][3]=v.w;
            *reinterpret_cast<float4*>(&xs[(ci * WROWS + lr) * 64 + col]) = v;
            float4 m = *reinterpret_cast<const float4*>(xin + ci * HW + gr * 64 + col);
            mu[ci][0] = 2.f*m.x - 1.f; mu[ci][1] = 2.f*m.y - 1.f;
            mu[ci][2] = 2.f*m.z - 1.f; mu[ci][3] = 2.f*m.w - 1.f;
        }
    }
    __syncthreads();

    int cur = 0;
    for (int step = 0; step < NSTEPS; ++step) {
        const StepC c = S.s[step];
        const int lo = base - 17 + step;
        const int hi = base + 49 - step;
        const bool active = rowv && (gr >= lo) && (gr < hi);

        if (active) {
            float acc[3][4];
            #pragma unroll
            for (int co = 0; co < 3; ++co)
                #pragma unroll
                for (int j = 0; j < 4; ++j) acc[co][j] = 0.f;

            #pragma unroll
            for (int ci = 0; ci < 3; ++ci) {
                float in0[6], in2[6], cen[6];
                // row gr-1 from LDS
                if (gr >= 1) {
                    float4 a = *reinterpret_cast<const float4*>(
                        &xs[cur * BUFF + (ci * WROWS + lr - 1) * 64 + col]);
                    in0[1]=a.x; in0[2]=a.y; in0[3]=a.z; in0[4]=a.w;
                    in0[0] = (cg > 0)  ? __shfl_up(a.w, 1)  : 0.f;
                    in0[5] = (cg < 15) ? __shfl_down(a.x, 1) : 0.f;
                } else {
                    #pragma unroll
                    for (int p = 0; p < 6; ++p) in0[p] = 0.f;
                }
                // row gr+1 from LDS
                if (gr + 1 < 64) {
                    float4 a = *reinterpret_cast<const float4*>(
                        &xs[cur * BUFF + (ci * WROWS + lr + 1) * 64 + col]);
                    in2[1]=a.x; in2[2]=a.y; in2[3]=a.z; in2[4]=a.w;
                    in2[0] = (cg > 0)  ? __shfl_up(a.w, 1)  : 0.f;
                    in2[5] = (cg < 15) ? __shfl_down(a.x, 1) : 0.f;
                } else {
                    #pragma unroll
                    for (int p = 0; p < 6; ++p) in2[p] = 0.f;
                }
                // own row from registers
                cen[0] = (cg > 0)  ? __shfl_up(xc[ci][3], 1)  : 0.f;
                cen[5] = (cg < 15) ? __shfl_down(xc[ci][0], 1) : 0.f;
                #pragma unroll
                for (int j = 0; j < 4; ++j) cen[j + 1] = xc[ci][j];

                #pragma unroll
                for (int co = 0; co < 3; ++co) {
                    const int wb = (co * 3 + ci) * 9;
                    #pragma unroll
                    for (int dw = 0; dw < 3; ++dw) {
                        const float w0t = Wn[wb + dw];
                        const float w1t = Wn[wb + 3 + dw];
                        const float w2t = Wn[wb + 6 + dw];
                        #pragma unroll
                        for (int j = 0; j < 4; ++j) {
                            acc[co][j] = fmaf(w0t, in0[j + dw],
                                         fmaf(w1t, cen[j + dw],
                                         fmaf(w2t, in2[j + dw], acc[co][j])));
                        }
                    }
                }
            }

            // EDM update
            const float* nz = noise + ((size_t)(step * NS + n)) * CHW;
            #pragma unroll
            for (int co = 0; co < 3; ++co) {
                float eps[4] = {0.f, 0.f, 0.f, 0.f};
                if (step < NSTEPS - 2) {
                    float4 e = *reinterpret_cast<const float4*>(nz + co * HW + gr * 64 + col);
                    eps[0]=e.x; eps[1]=e.y; eps[2]=e.z; eps[3]=e.w;
                }
                #pragma unroll
                for (int j = 0; j < 4; ++j) {
                    const float xv = xc[co][j];
                    const float f = fmaf(c.c_in, acc[co][j], bn[co]);
                    const float den = c.c_skip * xv + c.c_out * f;
                    const float dx = (den - xv) * c.inv_t + c.ce * (mu[co][j] - xv);
                    xc[co][j] = fmaf(c.two_dt, dx, fmaf(c.nc, eps[j], xv));
                }
            }
            // write new state to the other buffer
            #pragma unroll
            for (int co = 0; co < 3; ++co)
                *reinterpret_cast<float4*>(&xs[(cur ^ 1) * BUFF + (co * WROWS + lr) * 64 + col]) =
                    make_float4(xc[co][0], xc[co][1], xc[co][2], xc[co][3]);
        }
        __syncthreads();
        cur ^= 1;
    }

    // epilogue: xc holds final values for owned rows; write A=(x+1)/2 as bf16
    if (rowv && gr >= base && gr < base + 32) {
        unsigned short* Ao = Aout + (size_t)n * CHW;
        #pragma unroll
        for (int ci = 0; ci < 3; ++ci) {
            ushort4 o;
            o.x = f2bf((xc[ci][0] + 1.f) * 0.5f); o.y = f2bf((xc[ci][1] + 1.f) * 0.5f);
            o.z = f2bf((xc[ci][2] + 1.f) * 0.5f); o.w = f2bf((xc[ci][3] + 1.f) * 0.5f);
            *reinterpret_cast<ushort4*>(Ao + ci * HW + gr * 64 + col) = o;
        }
    }
}

// ---- GEMM: bf16 MFMA, A bf16 from ws, Wc f32 converted in-register, no LDS ----
__global__ __launch_bounds__(256)
void gemm_kernel(const unsigned short* __restrict__ Abf, const float* __restrict__ Wc,
                 float* __restrict__ part, int bkc)
{
    const int tid = threadIdx.x;
    const int wv = tid >> 6;
    const int lane = tid & 63;
    const int lrow = lane & 15;
    const int lk8 = (lane >> 4) << 3;
    const int ct = blockIdx.x & 15;
    const int kc = blockIdx.x >> 4;
    const int c0 = ct << 6;
    const int k0 = kc * bkc;

    v4f acc[2][4];
    #pragma unroll
    for (int rt = 0; rt < 2; ++rt)
        #pragma unroll
        for (int c4 = 0; c4 < 4; ++c4) acc[rt][c4] = (v4f)0.f;

    #pragma unroll 2
    for (int kk = 0; kk < bkc; kk += 32) {
        const int kb = k0 + kk + lk8;
        v8s a[2];
        #pragma unroll
        for (int rt = 0; rt < 2; ++rt)
            a[rt] = *reinterpret_cast<const v8s*>(Abf + (size_t)(wv * 32 + rt * 16 + lrow) * CHW + kb);
        v8s b[4];
        #pragma unroll
        for (int c4 = 0; c4 < 4; ++c4) {
            const int col = c0 + c4 * 16 + lrow;
            const bool cv = (col < NCLS);
            #pragma unroll
            for (int j = 0; j < 8; ++j) {
                const float f = cv ? Wc[(size_t)(kb + j) * NCLS + col] : 0.f;
                b[c4][j] = (short)f2bf(f);
            }
        }
        #pragma unroll
        for (int rt = 0; rt < 2; ++rt)
            #pragma unroll
            for (int c4 = 0; c4 < 4; ++c4)
                acc[rt][c4] = __builtin_amdgcn_mfma_f32_16x16x32_bf16(a[rt], b[c4], acc[rt][c4], 0, 0, 0);
    }

    float* pp = part + (size_t)kc * NS * NCLS;
    #pragma unroll
    for (int rt = 0; rt < 2; ++rt)
        #pragma unroll
        for (int c4 = 0; c4 < 4; ++c4) {
            const int col = c0 + c4 * 16 + lrow;
            if (col < NCLS) {
                #pragma unroll
                for (int r = 0; r < 4; ++r) {
                    const int row = wv * 32 + rt * 16 + (lane >> 4) * 4 + r;
                    pp[(size_t)row * NCLS + col] = acc[rt][c4][r];
                }
            }
        }
}

// ---- Reduce partials + bias + logsumexp over the 2 CEs ----
__global__ __launch_bounds__(256)
void lse_kernel(const float* __restrict__ part, const float* __restrict__ bcls,
                float* __restrict__ out, int ks)
{
    const int i = blockIdx.x * 256 + threadIdx.x;
    if (i >= 64 * NCLS) return;
    const int b = i / NCLS;
    const int k = i - b * NCLS;
    float l0 = bcls[k], l1 = bcls[k];
    for (int kc = 0; kc < ks; ++kc) {
        l0 += part[(size_t)kc * NS * NCLS + (size_t)b * NCLS + k];
        l1 += part[(size_t)kc * NS * NCLS + (size_t)(b + 64) * NCLS + k];
    }
    const float m = fmaxf(l0, l1);
    out[i] = m + logf(expf(l0 - m) + expf(l1 - m)) - 0.69314718055994530942f;
}

extern "C" void kernel_launch(void* const* d_in, const int* in_sizes, int n_in,
                              void* d_out, int out_size, void* d_ws, size_t ws_size,
                              hipStream_t stream) {
    const float* x       = (const float*)d_in[0];
    const float* latents = (const float*)d_in[1];
    const float* noise   = (const float*)d_in[2];
    const float* W_net   = (const float*)d_in[3];
    const float* b_net   = (const float*)d_in[4];
    const float* W_cls   = (const float*)d_in[5];
    const float* b_cls   = (const float*)d_in[6];
    float* out = (float*)d_out;

    unsigned short* Amat = (unsigned short*)d_ws;            // 128*12288 bf16
    const size_t amat_bytes = (size_t)NS * CHW * 2;
    float* part = (float*)((char*)d_ws + amat_bytes);

    // Karras sigma schedule in float64 (matches numpy), cast to f32
    Steps S;
    const double smin = pow(0.002, 1.0 / 7.0), smax = pow(80.0, 1.0 / 7.0);
    float tsf[NSTEPS + 1];
    for (int i = 0; i < NSTEPS; ++i) {
        double v = smax + (double)i / (double)(NSTEPS - 1) * (smin - smax);
        tsf[i] = (float)pow(v, 7.0);
    }
    tsf[NSTEPS] = 0.f;
    S.t0 = tsf[0];
    for (int i = 0; i < NSTEPS; ++i) {
        const float t = tsf[i], tn = tsf[i + 1];
        const float s2 = t * t, denom = s2 + 0.25f;
        StepC c;
        c.c_skip = 0.25f / denom;
        c.c_out  = t * 0.5f / sqrtf(denom);
        c.c_in   = 1.0f / sqrtf(denom);
        c.inv_t  = 1.0f / t;
        c.ce     = t / (0.04f + s2);
        const float dt = t - tn;
        c.two_dt = 2.f * dt;
        c.nc     = sqrtf(2.f * t * dt);
        c.pad    = 0.f;
        S.s[i] = c;
    }

    // K-split sized to workspace
    int KS = 32;
    while (KS > 1 && amat_bytes + (size_t)KS * NS * NCLS * 4 > ws_size) KS >>= 1;
    const int bkc = CHW / KS;

    sampler_kernel<<<NS * 2, 832, 0, stream>>>(x, latents, noise, W_net, b_net, Amat, S);
    gemm_kernel<<<16 * KS, 256, 0, stream>>>(Amat, W_cls, part, bkc);
    lse_kernel<<<(64 * NCLS + 255) / 256, 256, 0, stream>>>(part, b_cls, out, KS);
}

// Round 7
// 140.974 us; speedup vs baseline: 1.4828x; 1.4813x over previous
//
#include <hip/hip_runtime.h>
#include <math.h>

#define NSTEPS 18
#define NS 128      // N_CES*B
#define CHW 12288   // 3*64*64
#define HW 4096     // 64*64
#define NCLS 1000
#define NLOC 6      // steps per sampler launch
#define WIN 28      // window rows = 16 owned + 2*NLOC halo (clipped at edges)
#define BUFF6 (3 * WIN * 64)    // floats per LDS buffer

struct StepC { float c_skip, c_out, c_in, inv_t, ce, two_dt, nc, pad; };
struct Steps { StepC s[NSTEPS]; float t0; };

typedef __attribute__((ext_vector_type(8))) short v8s;
typedef __attribute__((ext_vector_type(4))) float v4f;

__device__ __forceinline__ unsigned short f2bf(float f) {
    unsigned int u = __float_as_uint(f);
    unsigned int r = (u + 0x7FFFu + ((u >> 16) & 1u)) >> 16;   // RNE
    return (unsigned short)r;
}

// ---- Sampler stage: 6 steps, 4 blocks/sample, 16 lanes/row (conflict-free),
// 448 threads + minwaves=2: the ONLY proven no-spill config (R3: 104 VGPR).
// (448,4)/(832,*) all cap VGPR=64 and spill 300MB (R2/R4/R5/R6).
__global__ __launch_bounds__(448, 2)
void sampler6_kernel(const float* __restrict__ src, float inscale,
                     const float* __restrict__ x, const float* __restrict__ noise,
                     const float* __restrict__ Wn_g, const float* __restrict__ bn_g,
                     float* __restrict__ Xout, unsigned short* __restrict__ Aout,
                     Steps S, int s0)
{
    __shared__ float xs[2 * BUFF6];    // 43 KB double buffer
    __shared__ float Wn[81];
    __shared__ float bn[3];
    const int tid = threadIdx.x;
    const int n = blockIdx.x >> 2;
    const int q = blockIdx.x & 3;
    const int base = q << 4;                       // first owned row
    const int w0 = (base - NLOC > 0) ? base - NLOC : 0;
    const int w1 = (base + 16 + NLOC < 64) ? base + 16 + NLOC : 64;
    const int wsize = w1 - w0;                     // 22 (edge) or 28

    if (tid < 81) Wn[tid] = Wn_g[tid];
    if (tid < 3)  bn[tid] = bn_g[tid];

    const int lr = tid >> 4;            // local row slot 0..27
    const int cg = tid & 15;            // col group
    const int col = cg << 2;
    const int gr = w0 + lr;             // global row
    const bool rowv = (lr < wsize);

    const float* sb = src + (size_t)n * CHW;
    const float* xin = x + (size_t)(n & 63) * CHW;

    // stage window into buf0 + own-row state in registers; preload mu = 2*x-1
    float xc[3][4], mu[3][4];
    if (rowv) {
        #pragma unroll
        for (int ci = 0; ci < 3; ++ci) {
            float4 v = *reinterpret_cast<const float4*>(sb + ci * HW + gr * 64 + col);
            v.x *= inscale; v.y *= inscale; v.z *= inscale; v.w *= inscale;
            xc[ci][0]=v.x; xc[ci][1]=v.y; xc[ci][2]=v.z; xc[ci][3]=v.w;
            *reinterpret_cast<float4*>(&xs[(ci * WIN + lr) * 64 + col]) = v;
            float4 m = *reinterpret_cast<const float4*>(xin + ci * HW + gr * 64 + col);
            mu[ci][0] = 2.f*m.x - 1.f; mu[ci][1] = 2.f*m.y - 1.f;
            mu[ci][2] = 2.f*m.z - 1.f; mu[ci][3] = 2.f*m.w - 1.f;
        }
    }
    __syncthreads();

    int cur = 0;
    for (int ls = 0; ls < NLOC; ++ls) {
        const StepC c = S.s[s0 + ls];
        const int rad = NLOC - 1 - ls;                 // correctness radius after this step
        const bool active = rowv && (gr >= base - rad) && (gr < base + 16 + rad);

        if (active) {
            float acc[3][4];
            #pragma unroll
            for (int co = 0; co < 3; ++co)
                #pragma unroll
                for (int j = 0; j < 4; ++j) acc[co][j] = 0.f;

            #pragma unroll
            for (int ci = 0; ci < 3; ++ci) {
                float in0[6], in2[6], cen[6];
                if (gr >= 1) {
                    float4 a = *reinterpret_cast<const float4*>(
                        &xs[cur * BUFF6 + (ci * WIN + lr - 1) * 64 + col]);
                    in0[1]=a.x; in0[2]=a.y; in0[3]=a.z; in0[4]=a.w;
                    in0[0] = (cg > 0)  ? __shfl_up(a.w, 1)  : 0.f;
                    in0[5] = (cg < 15) ? __shfl_down(a.x, 1) : 0.f;
                } else {
                    #pragma unroll
                    for (int p = 0; p < 6; ++p) in0[p] = 0.f;
                }
                if (gr + 1 < 64) {
                    float4 a = *reinterpret_cast<const float4*>(
                        &xs[cur * BUFF6 + (ci * WIN + lr + 1) * 64 + col]);
                    in2[1]=a.x; in2[2]=a.y; in2[3]=a.z; in2[4]=a.w;
                    in2[0] = (cg > 0)  ? __shfl_up(a.w, 1)  : 0.f;
                    in2[5] = (cg < 15) ? __shfl_down(a.x, 1) : 0.f;
                } else {
                    #pragma unroll
                    for (int p = 0; p < 6; ++p) in2[p] = 0.f;
                }
                cen[0] = (cg > 0)  ? __shfl_up(xc[ci][3], 1)  : 0.f;
                cen[5] = (cg < 15) ? __shfl_down(xc[ci][0], 1) : 0.f;
                #pragma unroll
                for (int j = 0; j < 4; ++j) cen[j + 1] = xc[ci][j];

                #pragma unroll
                for (int co = 0; co < 3; ++co) {
                    const int wb = (co * 3 + ci) * 9;
                    #pragma unroll
                    for (int dw = 0; dw < 3; ++dw) {
                        const float w0t = Wn[wb + dw];
                        const float w1t = Wn[wb + 3 + dw];
                        const float w2t = Wn[wb + 6 + dw];
                        #pragma unroll
                        for (int j = 0; j < 4; ++j) {
                            acc[co][j] = fmaf(w0t, in0[j + dw],
                                         fmaf(w1t, cen[j + dw],
                                         fmaf(w2t, in2[j + dw], acc[co][j])));
                        }
                    }
                }
            }

            // EDM update
            const int gstep = s0 + ls;
            const float* nz = noise + ((size_t)(gstep * NS + n)) * CHW;
            #pragma unroll
            for (int co = 0; co < 3; ++co) {
                float eps[4] = {0.f, 0.f, 0.f, 0.f};
                if (gstep < NSTEPS - 2) {
                    float4 e = *reinterpret_cast<const float4*>(nz + co * HW + gr * 64 + col);
                    eps[0]=e.x; eps[1]=e.y; eps[2]=e.z; eps[3]=e.w;
                }
                #pragma unroll
                for (int j = 0; j < 4; ++j) {
                    const float xv = xc[co][j];
                    const float f = fmaf(c.c_in, acc[co][j], bn[co]);
                    const float den = c.c_skip * xv + c.c_out * f;
                    const float dx = (den - xv) * c.inv_t + c.ce * (mu[co][j] - xv);
                    xc[co][j] = fmaf(c.two_dt, dx, fmaf(c.nc, eps[j], xv));
                }
            }
            // write new state to the other buffer
            #pragma unroll
            for (int co = 0; co < 3; ++co)
                *reinterpret_cast<float4*>(&xs[(cur ^ 1) * BUFF6 + (co * WIN + lr) * 64 + col]) =
                    make_float4(xc[co][0], xc[co][1], xc[co][2], xc[co][3]);
        }
        __syncthreads();
        cur ^= 1;
    }

    // epilogue: owned rows only
    if (rowv && gr >= base && gr < base + 16) {
        if (s0 + NLOC >= NSTEPS) {
            unsigned short* Ao = Aout + (size_t)n * CHW;
            #pragma unroll
            for (int ci = 0; ci < 3; ++ci) {
                ushort4 o;
                o.x = f2bf((xc[ci][0] + 1.f) * 0.5f); o.y = f2bf((xc[ci][1] + 1.f) * 0.5f);
                o.z = f2bf((xc[ci][2] + 1.f) * 0.5f); o.w = f2bf((xc[ci][3] + 1.f) * 0.5f);
                *reinterpret_cast<ushort4*>(Ao + ci * HW + gr * 64 + col) = o;
            }
        } else {
            float* Xo = Xout + (size_t)n * CHW;
            #pragma unroll
            for (int ci = 0; ci < 3; ++ci)
                *reinterpret_cast<float4*>(Xo + ci * HW + gr * 64 + col) =
                    make_float4(xc[ci][0], xc[ci][1], xc[ci][2], xc[ci][3]);
        }
    }
}

// ---- GEMM: bf16 MFMA, A bf16 from ws, Wc f32 converted in-register, no LDS ----
__global__ __launch_bounds__(256)
void gemm_kernel(const unsigned short* __restrict__ Abf, const float* __restrict__ Wc,
                 float* __restrict__ part, int bkc)
{
    const int tid = threadIdx.x;
    const int wv = tid >> 6;
    const int lane = tid & 63;
    const int lrow = lane & 15;
    const int lk8 = (lane >> 4) << 3;
    const int ct = blockIdx.x & 15;
    const int kc = blockIdx.x >> 4;
    const int c0 = ct << 6;
    const int k0 = kc * bkc;

    v4f acc[2][4];
    #pragma unroll
    for (int rt = 0; rt < 2; ++rt)
        #pragma unroll
        for (int c4 = 0; c4 < 4; ++c4) acc[rt][c4] = (v4f)0.f;

    #pragma unroll 2
    for (int kk = 0; kk < bkc; kk += 32) {
        const int kb = k0 + kk + lk8;
        v8s a[2];
        #pragma unroll
        for (int rt = 0; rt < 2; ++rt)
            a[rt] = *reinterpret_cast<const v8s*>(Abf + (size_t)(wv * 32 + rt * 16 + lrow) * CHW + kb);
        v8s b[4];
        #pragma unroll
        for (int c4 = 0; c4 < 4; ++c4) {
            const int col = c0 + c4 * 16 + lrow;
            const bool cv = (col < NCLS);
            #pragma unroll
            for (int j = 0; j < 8; ++j) {
                const float f = cv ? Wc[(size_t)(kb + j) * NCLS + col] : 0.f;
                b[c4][j] = (short)f2bf(f);
            }
        }
        #pragma unroll
        for (int rt = 0; rt < 2; ++rt)
            #pragma unroll
            for (int c4 = 0; c4 < 4; ++c4)
                acc[rt][c4] = __builtin_amdgcn_mfma_f32_16x16x32_bf16(a[rt], b[c4], acc[rt][c4], 0, 0, 0);
    }

    float* pp = part + (size_t)kc * NS * NCLS;
    #pragma unroll
    for (int rt = 0; rt < 2; ++rt)
        #pragma unroll
        for (int c4 = 0; c4 < 4; ++c4) {
            const int col = c0 + c4 * 16 + lrow;
            if (col < NCLS) {
                #pragma unroll
                for (int r = 0; r < 4; ++r) {
                    const int row = wv * 32 + rt * 16 + (lane >> 4) * 4 + r;
                    pp[(size_t)row * NCLS + col] = acc[rt][c4][r];
                }
            }
        }
}

// ---- Reduce partials + bias + logsumexp over the 2 CEs ----
__global__ __launch_bounds__(256)
void lse_kernel(const float* __restrict__ part, const float* __restrict__ bcls,
                float* __restrict__ out, int ks)
{
    const int i = blockIdx.x * 256 + threadIdx.x;
    if (i >= 64 * NCLS) return;
    const int b = i / NCLS;
    const int k = i - b * NCLS;
    float l0 = bcls[k], l1 = bcls[k];
    for (int kc = 0; kc < ks; ++kc) {
        l0 += part[(size_t)kc * NS * NCLS + (size_t)b * NCLS + k];
        l1 += part[(size_t)kc * NS * NCLS + (size_t)(b + 64) * NCLS + k];
    }
    const float m = fmaxf(l0, l1);
    out[i] = m + logf(expf(l0 - m) + expf(l1 - m)) - 0.69314718055994530942f;
}

extern "C" void kernel_launch(void* const* d_in, const int* in_sizes, int n_in,
                              void* d_out, int out_size, void* d_ws, size_t ws_size,
                              hipStream_t stream) {
    const float* x       = (const float*)d_in[0];
    const float* latents = (const float*)d_in[1];
    const float* noise   = (const float*)d_in[2];
    const float* W_net   = (const float*)d_in[3];
    const float* b_net   = (const float*)d_in[4];
    const float* W_cls   = (const float*)d_in[5];
    const float* b_cls   = (const float*)d_in[6];
    float* out = (float*)d_out;

    // workspace layout: XA | XB (f32 state ping-pong) | Amat (bf16) | part
    float* XA = (float*)d_ws;
    float* XB = XA + (size_t)NS * CHW;
    unsigned short* Amat = (unsigned short*)(XB + (size_t)NS * CHW);
    const size_t head_bytes = (size_t)NS * CHW * 4 * 2 + (size_t)NS * CHW * 2;
    float* part = (float*)((char*)d_ws + head_bytes);

    // Karras sigma schedule in float64 (matches numpy), cast to f32
    Steps S;
    const double smin = pow(0.002, 1.0 / 7.0), smax = pow(80.0, 1.0 / 7.0);
    float tsf[NSTEPS + 1];
    for (int i = 0; i < NSTEPS; ++i) {
        double v = smax + (double)i / (double)(NSTEPS - 1) * (smin - smax);
        tsf[i] = (float)pow(v, 7.0);
    }
    tsf[NSTEPS] = 0.f;
    S.t0 = tsf[0];
    for (int i = 0; i < NSTEPS; ++i) {
        const float t = tsf[i], tn = tsf[i + 1];
        const float s2 = t * t, denom = s2 + 0.25f;
        StepC c;
        c.c_skip = 0.25f / denom;
        c.c_out  = t * 0.5f / sqrtf(denom);
        c.c_in   = 1.0f / sqrtf(denom);
        c.inv_t  = 1.0f / t;
        c.ce     = t / (0.04f + s2);
        const float dt = t - tn;
        c.two_dt = 2.f * dt;
        c.nc     = sqrtf(2.f * t * dt);
        c.pad    = 0.f;
        S.s[i] = c;
    }

    // K-split sized to remaining workspace
    int KS = 32;
    while (KS > 1 && head_bytes + (size_t)KS * NS * NCLS * 4 > ws_size) KS >>= 1;
    const int bkc = CHW / KS;

    sampler6_kernel<<<NS * 4, 448, 0, stream>>>(latents, S.t0, x, noise, W_net, b_net, XA, Amat, S, 0);
    sampler6_kernel<<<NS * 4, 448, 0, stream>>>(XA, 1.f, x, noise, W_net, b_net, XB, Amat, S, 6);
    sampler6_kernel<<<NS * 4, 448, 0, stream>>>(XB, 1.f, x, noise, W_net, b_net, XB, Amat, S, 12);
    gemm_kernel<<<16 * KS, 256, 0, stream>>>(Amat, W_cls, part, bkc);
    lse_kernel<<<(64 * NCLS + 255) / 256, 256, 0, stream>>>(part, b_cls, out, KS);
}

// Round 8
// 126.061 us; speedup vs baseline: 1.6582x; 1.1183x over previous
//
#include <hip/hip_runtime.h>
#include <math.h>

#define NSTEPS 18
#define NS 128      // N_CES*B
#define CHW 12288   // 3*64*64
#define HW 4096     // 64*64
#define NCLS 1000
#define NLOC 6      // steps per sampler launch
#define WIN 28      // window rows = 16 owned + 2*NLOC halo (clipped at edges)
#define BUFF6 (3 * WIN * 64)    // floats per LDS buffer

struct StepC { float c_skip, c_out, c_in, inv_t, ce, two_dt, nc, pad; };
struct Steps { StepC s[NSTEPS]; float t0; };

typedef __attribute__((ext_vector_type(8))) short v8s;
typedef __attribute__((ext_vector_type(4))) float v4f;

__device__ __forceinline__ unsigned short f2bf(float f) {
    unsigned int u = __float_as_uint(f);
    unsigned int r = (u + 0x7FFFu + ((u >> 16) & 1u)) >> 16;   // RNE
    return (unsigned short)r;
}

// ---- Sampler stage: 6 steps, 4 blocks/sample, 16 lanes/row.
// 448 threads + minwaves=2: the ONLY proven no-spill config (R3/R7: ~104 VGPR).
// Weights/bias read via UNIFORM global addresses -> s_load/SGPR (not LDS):
// R7 was LDS-issue-bound on 81 ds_read_b32 weight reads per thread-step.
// Halo columns read directly from LDS (b32) instead of ds_bpermute shfls.
__global__ __launch_bounds__(448, 2)
void sampler6_kernel(const float* __restrict__ src, float inscale,
                     const float* __restrict__ x, const float* __restrict__ noise,
                     const float* __restrict__ Wn_g, const float* __restrict__ bn_g,
                     float* __restrict__ Xout, unsigned short* __restrict__ Aout,
                     Steps S, int s0)
{
    __shared__ float xs[2 * BUFF6];    // 43 KB double buffer
    const int tid = threadIdx.x;
    const int n = blockIdx.x >> 2;
    const int q = blockIdx.x & 3;
    const int base = q << 4;                       // first owned row
    const int w0 = (base - NLOC > 0) ? base - NLOC : 0;
    const int w1 = (base + 16 + NLOC < 64) ? base + 16 + NLOC : 64;
    const int wsize = w1 - w0;                     // 22 (edge) or 28

    const int lr = tid >> 4;            // local row slot 0..27
    const int cg = tid & 15;            // col group
    const int col = cg << 2;
    const int gr = w0 + lr;             // global row
    const bool rowv = (lr < wsize);

    const float* sb = src + (size_t)n * CHW;
    const float* xin = x + (size_t)(n & 63) * CHW;

    // stage window into buf0 + own-row state in registers; preload mu = 2*x-1
    float xc[3][4], mu[3][4];
    if (rowv) {
        #pragma unroll
        for (int ci = 0; ci < 3; ++ci) {
            float4 v = *reinterpret_cast<const float4*>(sb + ci * HW + gr * 64 + col);
            v.x *= inscale; v.y *= inscale; v.z *= inscale; v.w *= inscale;
            xc[ci][0]=v.x; xc[ci][1]=v.y; xc[ci][2]=v.z; xc[ci][3]=v.w;
            *reinterpret_cast<float4*>(&xs[(ci * WIN + lr) * 64 + col]) = v;
            float4 m = *reinterpret_cast<const float4*>(xin + ci * HW + gr * 64 + col);
            mu[ci][0] = 2.f*m.x - 1.f; mu[ci][1] = 2.f*m.y - 1.f;
            mu[ci][2] = 2.f*m.z - 1.f; mu[ci][3] = 2.f*m.w - 1.f;
        }
    }
    __syncthreads();

    int cur = 0;
    for (int ls = 0; ls < NLOC; ++ls) {
        const StepC c = S.s[s0 + ls];
        const int rad = NLOC - 1 - ls;                 // correctness radius after this step
        const bool active = rowv && (gr >= base - rad) && (gr < base + 16 + rad);

        if (active) {
            float acc[3][4];
            #pragma unroll
            for (int co = 0; co < 3; ++co)
                #pragma unroll
                for (int j = 0; j < 4; ++j) acc[co][j] = 0.f;

            #pragma unroll
            for (int ci = 0; ci < 3; ++ci) {
                float in0[6], in2[6], cen[6];
                const float* bcur = &xs[cur * BUFF6 + ci * (WIN * 64)];
                // row gr-1 (LDS)
                if (gr >= 1) {
                    const float* rp = bcur + (lr - 1) * 64 + col;
                    float4 a = *reinterpret_cast<const float4*>(rp);
                    in0[1]=a.x; in0[2]=a.y; in0[3]=a.z; in0[4]=a.w;
                    in0[0] = (cg > 0)  ? rp[-1] : 0.f;
                    in0[5] = (cg < 15) ? rp[4]  : 0.f;
                } else {
                    #pragma unroll
                    for (int p = 0; p < 6; ++p) in0[p] = 0.f;
                }
                // row gr+1 (LDS)
                if (gr + 1 < 64) {
                    const float* rp = bcur + (lr + 1) * 64 + col;
                    float4 a = *reinterpret_cast<const float4*>(rp);
                    in2[1]=a.x; in2[2]=a.y; in2[3]=a.z; in2[4]=a.w;
                    in2[0] = (cg > 0)  ? rp[-1] : 0.f;
                    in2[5] = (cg < 15) ? rp[4]  : 0.f;
                } else {
                    #pragma unroll
                    for (int p = 0; p < 6; ++p) in2[p] = 0.f;
                }
                // own row: center 4 from registers, edges from LDS
                {
                    const float* rp = bcur + lr * 64 + col;
                    cen[0] = (cg > 0)  ? rp[-1] : 0.f;
                    cen[5] = (cg < 15) ? rp[4]  : 0.f;
                    #pragma unroll
                    for (int j = 0; j < 4; ++j) cen[j + 1] = xc[ci][j];
                }

                #pragma unroll
                for (int co = 0; co < 3; ++co) {
                    const int wb = (co * 3 + ci) * 9;
                    #pragma unroll
                    for (int dw = 0; dw < 3; ++dw) {
                        // uniform addresses -> scalar loads (SGPR), no LDS traffic
                        const float w0t = Wn_g[wb + dw];
                        const float w1t = Wn_g[wb + 3 + dw];
                        const float w2t = Wn_g[wb + 6 + dw];
                        #pragma unroll
                        for (int j = 0; j < 4; ++j) {
                            acc[co][j] = fmaf(w0t, in0[j + dw],
                                         fmaf(w1t, cen[j + dw],
                                         fmaf(w2t, in2[j + dw], acc[co][j])));
                        }
                    }
                }
            }

            // EDM update
            const int gstep = s0 + ls;
            const float* nz = noise + ((size_t)(gstep * NS + n)) * CHW;
            #pragma unroll
            for (int co = 0; co < 3; ++co) {
                float eps[4] = {0.f, 0.f, 0.f, 0.f};
                if (gstep < NSTEPS - 2) {
                    float4 e = *reinterpret_cast<const float4*>(nz + co * HW + gr * 64 + col);
                    eps[0]=e.x; eps[1]=e.y; eps[2]=e.z; eps[3]=e.w;
                }
                const float bnv = bn_g[co];
                #pragma unroll
                for (int j = 0; j < 4; ++j) {
                    const float xv = xc[co][j];
                    const float f = fmaf(c.c_in, acc[co][j], bnv);
                    const float den = c.c_skip * xv + c.c_out * f;
                    const float dx = (den - xv) * c.inv_t + c.ce * (mu[co][j] - xv);
                    xc[co][j] = fmaf(c.two_dt, dx, fmaf(c.nc, eps[j], xv));
                }
            }
            // write new state to the other buffer
            #pragma unroll
            for (int co = 0; co < 3; ++co)
                *reinterpret_cast<float4*>(&xs[(cur ^ 1) * BUFF6 + (co * WIN + lr) * 64 + col]) =
                    make_float4(xc[co][0], xc[co][1], xc[co][2], xc[co][3]);
        }
        __syncthreads();
        cur ^= 1;
    }

    // epilogue: owned rows only
    if (rowv && gr >= base && gr < base + 16) {
        if (s0 + NLOC >= NSTEPS) {
            unsigned short* Ao = Aout + (size_t)n * CHW;
            #pragma unroll
            for (int ci = 0; ci < 3; ++ci) {
                ushort4 o;
                o.x = f2bf((xc[ci][0] + 1.f) * 0.5f); o.y = f2bf((xc[ci][1] + 1.f) * 0.5f);
                o.z = f2bf((xc[ci][2] + 1.f) * 0.5f); o.w = f2bf((xc[ci][3] + 1.f) * 0.5f);
                *reinterpret_cast<ushort4*>(Ao + ci * HW + gr * 64 + col) = o;
            }
        } else {
            float* Xo = Xout + (size_t)n * CHW;
            #pragma unroll
            for (int ci = 0; ci < 3; ++ci)
                *reinterpret_cast<float4*>(Xo + ci * HW + gr * 64 + col) =
                    make_float4(xc[ci][0], xc[ci][1], xc[ci][2], xc[ci][3]);
        }
    }
}

// ---- GEMM: bf16 MFMA, A bf16 from ws, Wc f32 converted in-register, no LDS ----
__global__ __launch_bounds__(256)
void gemm_kernel(const unsigned short* __restrict__ Abf, const float* __restrict__ Wc,
                 float* __restrict__ part, int bkc)
{
    const int tid = threadIdx.x;
    const int wv = tid >> 6;
    const int lane = tid & 63;
    const int lrow = lane & 15;
    const int lk8 = (lane >> 4) << 3;
    const int ct = blockIdx.x & 15;
    const int kc = blockIdx.x >> 4;
    const int c0 = ct << 6;
    const int k0 = kc * bkc;

    v4f acc[2][4];
    #pragma unroll
    for (int rt = 0; rt < 2; ++rt)
        #pragma unroll
        for (int c4 = 0; c4 < 4; ++c4) acc[rt][c4] = (v4f)0.f;

    #pragma unroll 2
    for (int kk = 0; kk < bkc; kk += 32) {
        const int kb = k0 + kk + lk8;
        v8s a[2];
        #pragma unroll
        for (int rt = 0; rt < 2; ++rt)
            a[rt] = *reinterpret_cast<const v8s*>(Abf + (size_t)(wv * 32 + rt * 16 + lrow) * CHW + kb);
        v8s b[4];
        #pragma unroll
        for (int c4 = 0; c4 < 4; ++c4) {
            const int col = c0 + c4 * 16 + lrow;
            const bool cv = (col < NCLS);
            #pragma unroll
            for (int j = 0; j < 8; ++j) {
                const float f = cv ? Wc[(size_t)(kb + j) * NCLS + col] : 0.f;
                b[c4][j] = (short)f2bf(f);
            }
        }
        #pragma unroll
        for (int rt = 0; rt < 2; ++rt)
            #pragma unroll
            for (int c4 = 0; c4 < 4; ++c4)
                acc[rt][c4] = __builtin_amdgcn_mfma_f32_16x16x32_bf16(a[rt], b[c4], acc[rt][c4], 0, 0, 0);
    }

    float* pp = part + (size_t)kc * NS * NCLS;
    #pragma unroll
    for (int rt = 0; rt < 2; ++rt)
        #pragma unroll
        for (int c4 = 0; c4 < 4; ++c4) {
            const int col = c0 + c4 * 16 + lrow;
            if (col < NCLS) {
                #pragma unroll
                for (int r = 0; r < 4; ++r) {
                    const int row = wv * 32 + rt * 16 + (lane >> 4) * 4 + r;
                    pp[(size_t)row * NCLS + col] = acc[rt][c4][r];
                }
            }
        }
}

// ---- Reduce partials + bias + logsumexp over the 2 CEs ----
__global__ __launch_bounds__(256)
void lse_kernel(const float* __restrict__ part, const float* __restrict__ bcls,
                float* __restrict__ out, int ks)
{
    const int i = blockIdx.x * 256 + threadIdx.x;
    if (i >= 64 * NCLS) return;
    const int b = i / NCLS;
    const int k = i - b * NCLS;
    float l0 = bcls[k], l1 = bcls[k];
    for (int kc = 0; kc < ks; ++kc) {
        l0 += part[(size_t)kc * NS * NCLS + (size_t)b * NCLS + k];
        l1 += part[(size_t)kc * NS * NCLS + (size_t)(b + 64) * NCLS + k];
    }
    const float m = fmaxf(l0, l1);
    out[i] = m + logf(expf(l0 - m) + expf(l1 - m)) - 0.69314718055994530942f;
}

extern "C" void kernel_launch(void* const* d_in, const int* in_sizes, int n_in,
                              void* d_out, int out_size, void* d_ws, size_t ws_size,
                              hipStream_t stream) {
    const float* x       = (const float*)d_in[0];
    const float* latents = (const float*)d_in[1];
    const float* noise   = (const float*)d_in[2];
    const float* W_net   = (const float*)d_in[3];
    const float* b_net   = (const float*)d_in[4];
    const float* W_cls   = (const float*)d_in[5];
    const float* b_cls   = (const float*)d_in[6];
    float* out = (float*)d_out;

    // workspace layout: XA | XB (f32 state ping-pong) | Amat (bf16) | part
    float* XA = (float*)d_ws;
    float* XB = XA + (size_t)NS * CHW;
    unsigned short* Amat = (unsigned short*)(XB + (size_t)NS * CHW);
    const size_t head_bytes = (size_t)NS * CHW * 4 * 2 + (size_t)NS * CHW * 2;
    float* part = (float*)((char*)d_ws + head_bytes);

    // Karras sigma schedule in float64 (matches numpy), cast to f32
    Steps S;
    const double smin = pow(0.002, 1.0 / 7.0), smax = pow(80.0, 1.0 / 7.0);
    float tsf[NSTEPS + 1];
    for (int i = 0; i < NSTEPS; ++i) {
        double v = smax + (double)i / (double)(NSTEPS - 1) * (smin - smax);
        tsf[i] = (float)pow(v, 7.0);
    }
    tsf[NSTEPS] = 0.f;
    S.t0 = tsf[0];
    for (int i = 0; i < NSTEPS; ++i) {
        const float t = tsf[i], tn = tsf[i + 1];
        const float s2 = t * t, denom = s2 + 0.25f;
        StepC c;
        c.c_skip = 0.25f / denom;
        c.c_out  = t * 0.5f / sqrtf(denom);
        c.c_in   = 1.0f / sqrtf(denom);
        c.inv_t  = 1.0f / t;
        c.ce     = t / (0.04f + s2);
        const float dt = t - tn;
        c.two_dt = 2.f * dt;
        c.nc     = sqrtf(2.f * t * dt);
        c.pad    = 0.f;
        S.s[i] = c;
    }

    // K-split sized to remaining workspace
    int KS = 32;
    while (KS > 1 && head_bytes + (size_t)KS * NS * NCLS * 4 > ws_size) KS >>= 1;
    const int bkc = CHW / KS;

    sampler6_kernel<<<NS * 4, 448, 0, stream>>>(latents, S.t0, x, noise, W_net, b_net, XA, Amat, S, 0);
    sampler6_kernel<<<NS * 4, 448, 0, stream>>>(XA, 1.f, x, noise, W_net, b_net, XB, Amat, S, 6);
    sampler6_kernel<<<NS * 4, 448, 0, stream>>>(XB, 1.f, x, noise, W_net, b_net, XB, Amat, S, 12);
    gemm_kernel<<<16 * KS, 256, 0, stream>>>(Amat, W_cls, part, bkc);
    lse_kernel<<<(64 * NCLS + 255) / 256, 256, 0, stream>>>(part, b_cls, out, KS);
}

// Round 9
// 120.749 us; speedup vs baseline: 1.7311x; 1.0440x over previous
//
#include <hip/hip_runtime.h>
#include <math.h>

#define NSTEPS 18
#define NS 128      // N_CES*B
#define CHW 12288   // 3*64*64
#define HW 4096     // 64*64
#define NCLS 1000
#define NLOC 6      // steps per sampler launch
#define WIN 28      // window rows = 16 owned + 2*NLOC halo (clipped at edges)
#define BUFF6 (3 * WIN * 64)    // floats per LDS buffer

struct StepC { float c_skip, c_out, c_in, inv_t, ce, two_dt, nc, pad; };
struct Steps { StepC s[NSTEPS]; float t0; };

typedef __attribute__((ext_vector_type(8))) short v8s;
typedef __attribute__((ext_vector_type(4))) float v4f;

__device__ __forceinline__ unsigned short f2bf(float f) {
    unsigned int u = __float_as_uint(f);
    unsigned int r = (u + 0x7FFFu + ((u >> 16) & 1u)) >> 16;   // RNE
    return (unsigned short)r;
}

// ---- Sampler stage: 6 steps, 4 blocks/sample, 16 lanes/row.
// 448 threads + minwaves=2: the ONLY proven no-spill config (~104 VGPR).
// Weights live in LDS reordered ci-major; per ci they are loaded as 7
// ds_read_b128 BROADCASTS into regs. Rationale: s_load(SMEM) shares lgkmcnt
// with DS and retires out-of-order -> every s_load use forces lgkmcnt(0),
// draining the conv's ds_reads (R8 symptom). All-DS keeps in-order fine-
// grained waits. Noise is prefetched before the conv to hide HBM latency.
__global__ __launch_bounds__(448, 2)
void sampler6_kernel(const float* __restrict__ src, float inscale,
                     const float* __restrict__ x, const float* __restrict__ noise,
                     const float* __restrict__ Wn_g, const float* __restrict__ bn_g,
                     float* __restrict__ Xout, unsigned short* __restrict__ Aout,
                     Steps S, int s0)
{
    __shared__ float xs[2 * BUFF6];    // 43 KB double buffer
    __shared__ float Wl[3 * 32 + 4];   // per-ci 27 weights @ stride 32, + bias @ 96
    const int tid = threadIdx.x;
    const int n = blockIdx.x >> 2;
    const int q = blockIdx.x & 3;
    const int base = q << 4;                       // first owned row
    const int w0 = (base - NLOC > 0) ? base - NLOC : 0;
    const int w1 = (base + 16 + NLOC < 64) ? base + 16 + NLOC : 64;
    const int wsize = w1 - w0;                     // 22 (edge) or 28

    // stage weights reordered: Wl[ci*32 + co*9 + dh*3 + dw]
    if (tid < 81) {
        const int co = tid / 27, r = tid % 27;
        const int ci = r / 9, r2 = r % 9;
        Wl[ci * 32 + co * 9 + r2] = Wn_g[tid];
    } else if (tid < 84) {
        Wl[96 + (tid - 81)] = bn_g[tid - 81];
    }

    const int lr = tid >> 4;            // local row slot 0..27
    const int cg = tid & 15;            // col group
    const int col = cg << 2;
    const int gr = w0 + lr;             // global row
    const bool rowv = (lr < wsize);

    const float* sb = src + (size_t)n * CHW;
    const float* xin = x + (size_t)(n & 63) * CHW;

    // stage window into buf0 + own-row state in registers; preload mu = 2*x-1
    float xc[3][4], mu[3][4];
    if (rowv) {
        #pragma unroll
        for (int ci = 0; ci < 3; ++ci) {
            float4 v = *reinterpret_cast<const float4*>(sb + ci * HW + gr * 64 + col);
            v.x *= inscale; v.y *= inscale; v.z *= inscale; v.w *= inscale;
            xc[ci][0]=v.x; xc[ci][1]=v.y; xc[ci][2]=v.z; xc[ci][3]=v.w;
            *reinterpret_cast<float4*>(&xs[(ci * WIN + lr) * 64 + col]) = v;
            float4 m = *reinterpret_cast<const float4*>(xin + ci * HW + gr * 64 + col);
            mu[ci][0] = 2.f*m.x - 1.f; mu[ci][1] = 2.f*m.y - 1.f;
            mu[ci][2] = 2.f*m.z - 1.f; mu[ci][3] = 2.f*m.w - 1.f;
        }
    }
    __syncthreads();

    int cur = 0;
    for (int ls = 0; ls < NLOC; ++ls) {
        const StepC c = S.s[s0 + ls];
        const int gstep = s0 + ls;
        const int rad = NLOC - 1 - ls;                 // correctness radius after this step
        const bool active = rowv && (gr >= base - rad) && (gr < base + 16 + rad);

        if (active) {
            // prefetch noise FIRST so HBM latency hides under the conv
            float4 e0, e1, e2;
            e0 = make_float4(0.f,0.f,0.f,0.f); e1 = e0; e2 = e0;
            if (gstep < NSTEPS - 2) {
                const float* nz = noise + ((size_t)(gstep * NS + n)) * CHW + gr * 64 + col;
                e0 = *reinterpret_cast<const float4*>(nz);
                e1 = *reinterpret_cast<const float4*>(nz + HW);
                e2 = *reinterpret_cast<const float4*>(nz + 2 * HW);
            }

            float acc[3][4];
            #pragma unroll
            for (int co = 0; co < 3; ++co)
                #pragma unroll
                for (int j = 0; j < 4; ++j) acc[co][j] = 0.f;

            #pragma unroll
            for (int ci = 0; ci < 3; ++ci) {
                // broadcast-load this ci's 27 weights (7 x b128, all lanes same addr)
                float wf[28];
                #pragma unroll
                for (int t = 0; t < 7; ++t) {
                    float4 wv = *reinterpret_cast<const float4*>(&Wl[ci * 32 + t * 4]);
                    wf[t*4+0] = wv.x; wf[t*4+1] = wv.y; wf[t*4+2] = wv.z; wf[t*4+3] = wv.w;
                }

                float in0[6], in2[6], cen[6];
                const float* bcur = &xs[cur * BUFF6 + ci * (WIN * 64)];
                if (gr >= 1) {
                    const float* rp = bcur + (lr - 1) * 64 + col;
                    float4 a = *reinterpret_cast<const float4*>(rp);
                    in0[1]=a.x; in0[2]=a.y; in0[3]=a.z; in0[4]=a.w;
                    in0[0] = (cg > 0)  ? rp[-1] : 0.f;
                    in0[5] = (cg < 15) ? rp[4]  : 0.f;
                } else {
                    #pragma unroll
                    for (int p = 0; p < 6; ++p) in0[p] = 0.f;
                }
                if (gr + 1 < 64) {
                    const float* rp = bcur + (lr + 1) * 64 + col;
                    float4 a = *reinterpret_cast<const float4*>(rp);
                    in2[1]=a.x; in2[2]=a.y; in2[3]=a.z; in2[4]=a.w;
                    in2[0] = (cg > 0)  ? rp[-1] : 0.f;
                    in2[5] = (cg < 15) ? rp[4]  : 0.f;
                } else {
                    #pragma unroll
                    for (int p = 0; p < 6; ++p) in2[p] = 0.f;
                }
                {
                    const float* rp = bcur + lr * 64 + col;
                    cen[0] = (cg > 0)  ? rp[-1] : 0.f;
                    cen[5] = (cg < 15) ? rp[4]  : 0.f;
                    #pragma unroll
                    for (int j = 0; j < 4; ++j) cen[j + 1] = xc[ci][j];
                }

                #pragma unroll
                for (int co = 0; co < 3; ++co) {
                    #pragma unroll
                    for (int dw = 0; dw < 3; ++dw) {
                        const float w0t = wf[co * 9 + dw];
                        const float w1t = wf[co * 9 + 3 + dw];
                        const float w2t = wf[co * 9 + 6 + dw];
                        #pragma unroll
                        for (int j = 0; j < 4; ++j) {
                            acc[co][j] = fmaf(w0t, in0[j + dw],
                                         fmaf(w1t, cen[j + dw],
                                         fmaf(w2t, in2[j + dw], acc[co][j])));
                        }
                    }
                }
            }

            // EDM update (noise already in regs)
            const float bn0 = Wl[96], bn1 = Wl[97], bn2 = Wl[98];
            const float eps[3][4] = {{e0.x,e0.y,e0.z,e0.w},
                                     {e1.x,e1.y,e1.z,e1.w},
                                     {e2.x,e2.y,e2.z,e2.w}};
            const float bnv[3] = {bn0, bn1, bn2};
            #pragma unroll
            for (int co = 0; co < 3; ++co) {
                #pragma unroll
                for (int j = 0; j < 4; ++j) {
                    const float xv = xc[co][j];
                    const float f = fmaf(c.c_in, acc[co][j], bnv[co]);
                    const float den = c.c_skip * xv + c.c_out * f;
                    const float dx = (den - xv) * c.inv_t + c.ce * (mu[co][j] - xv);
                    xc[co][j] = fmaf(c.two_dt, dx, fmaf(c.nc, eps[co][j], xv));
                }
            }
            // write new state to the other buffer
            #pragma unroll
            for (int co = 0; co < 3; ++co)
                *reinterpret_cast<float4*>(&xs[(cur ^ 1) * BUFF6 + (co * WIN + lr) * 64 + col]) =
                    make_float4(xc[co][0], xc[co][1], xc[co][2], xc[co][3]);
        }
        __syncthreads();
        cur ^= 1;
    }

    // epilogue: owned rows only
    if (rowv && gr >= base && gr < base + 16) {
        if (s0 + NLOC >= NSTEPS) {
            unsigned short* Ao = Aout + (size_t)n * CHW;
            #pragma unroll
            for (int ci = 0; ci < 3; ++ci) {
                ushort4 o;
                o.x = f2bf((xc[ci][0] + 1.f) * 0.5f); o.y = f2bf((xc[ci][1] + 1.f) * 0.5f);
                o.z = f2bf((xc[ci][2] + 1.f) * 0.5f); o.w = f2bf((xc[ci][3] + 1.f) * 0.5f);
                *reinterpret_cast<ushort4*>(Ao + ci * HW + gr * 64 + col) = o;
            }
        } else {
            float* Xo = Xout + (size_t)n * CHW;
            #pragma unroll
            for (int ci = 0; ci < 3; ++ci)
                *reinterpret_cast<float4*>(Xo + ci * HW + gr * 64 + col) =
                    make_float4(xc[ci][0], xc[ci][1], xc[ci][2], xc[ci][3]);
        }
    }
}

// ---- GEMM: bf16 MFMA, A bf16 from ws, Wc f32 converted in-register, no LDS ----
__global__ __launch_bounds__(256)
void gemm_kernel(const unsigned short* __restrict__ Abf, const float* __restrict__ Wc,
                 float* __restrict__ part, int bkc)
{
    const int tid = threadIdx.x;
    const int wv = tid >> 6;
    const int lane = tid & 63;
    const int lrow = lane & 15;
    const int lk8 = (lane >> 4) << 3;
    const int ct = blockIdx.x & 15;
    const int kc = blockIdx.x >> 4;
    const int c0 = ct << 6;
    const int k0 = kc * bkc;

    v4f acc[2][4];
    #pragma unroll
    for (int rt = 0; rt < 2; ++rt)
        #pragma unroll
        for (int c4 = 0; c4 < 4; ++c4) acc[rt][c4] = (v4f)0.f;

    #pragma unroll 2
    for (int kk = 0; kk < bkc; kk += 32) {
        const int kb = k0 + kk + lk8;
        v8s a[2];
        #pragma unroll
        for (int rt = 0; rt < 2; ++rt)
            a[rt] = *reinterpret_cast<const v8s*>(Abf + (size_t)(wv * 32 + rt * 16 + lrow) * CHW + kb);
        v8s b[4];
        #pragma unroll
        for (int c4 = 0; c4 < 4; ++c4) {
            const int col = c0 + c4 * 16 + lrow;
            const bool cv = (col < NCLS);
            #pragma unroll
            for (int j = 0; j < 8; ++j) {
                const float f = cv ? Wc[(size_t)(kb + j) * NCLS + col] : 0.f;
                b[c4][j] = (short)f2bf(f);
            }
        }
        #pragma unroll
        for (int rt = 0; rt < 2; ++rt)
            #pragma unroll
            for (int c4 = 0; c4 < 4; ++c4)
                acc[rt][c4] = __builtin_amdgcn_mfma_f32_16x16x32_bf16(a[rt], b[c4], acc[rt][c4], 0, 0, 0);
    }

    float* pp = part + (size_t)kc * NS * NCLS;
    #pragma unroll
    for (int rt = 0; rt < 2; ++rt)
        #pragma unroll
        for (int c4 = 0; c4 < 4; ++c4) {
            const int col = c0 + c4 * 16 + lrow;
            if (col < NCLS) {
                #pragma unroll
                for (int r = 0; r < 4; ++r) {
                    const int row = wv * 32 + rt * 16 + (lane >> 4) * 4 + r;
                    pp[(size_t)row * NCLS + col] = acc[rt][c4][r];
                }
            }
        }
}

// ---- Reduce partials + bias + logsumexp over the 2 CEs ----
__global__ __launch_bounds__(256)
void lse_kernel(const float* __restrict__ part, const float* __restrict__ bcls,
                float* __restrict__ out, int ks)
{
    const int i = blockIdx.x * 256 + threadIdx.x;
    if (i >= 64 * NCLS) return;
    const int b = i / NCLS;
    const int k = i - b * NCLS;
    float l0 = bcls[k], l1 = bcls[k];
    for (int kc = 0; kc < ks; ++kc) {
        l0 += part[(size_t)kc * NS * NCLS + (size_t)b * NCLS + k];
        l1 += part[(size_t)kc * NS * NCLS + (size_t)(b + 64) * NCLS + k];
    }
    const float m = fmaxf(l0, l1);
    out[i] = m + logf(expf(l0 - m) + expf(l1 - m)) - 0.69314718055994530942f;
}

extern "C" void kernel_launch(void* const* d_in, const int* in_sizes, int n_in,
                              void* d_out, int out_size, void* d_ws, size_t ws_size,
                              hipStream_t stream) {
    const float* x       = (const float*)d_in[0];
    const float* latents = (const float*)d_in[1];
    const float* noise   = (const float*)d_in[2];
    const float* W_net   = (const float*)d_in[3];
    const float* b_net   = (const float*)d_in[4];
    const float* W_cls   = (const float*)d_in[5];
    const float* b_cls   = (const float*)d_in[6];
    float* out = (float*)d_out;

    // workspace layout: XA | XB (f32 state ping-pong) | Amat (bf16) | part
    float* XA = (float*)d_ws;
    float* XB = XA + (size_t)NS * CHW;
    unsigned short* Amat = (unsigned short*)(XB + (size_t)NS * CHW);
    const size_t head_bytes = (size_t)NS * CHW * 4 * 2 + (size_t)NS * CHW * 2;
    float* part = (float*)((char*)d_ws + head_bytes);

    // Karras sigma schedule in float64 (matches numpy), cast to f32
    Steps S;
    const double smin = pow(0.002, 1.0 / 7.0), smax = pow(80.0, 1.0 / 7.0);
    float tsf[NSTEPS + 1];
    for (int i = 0; i < NSTEPS; ++i) {
        double v = smax + (double)i / (double)(NSTEPS - 1) * (smin - smax);
        tsf[i] = (float)pow(v, 7.0);
    }
    tsf[NSTEPS] = 0.f;
    S.t0 = tsf[0];
    for (int i = 0; i < NSTEPS; ++i) {
        const float t = tsf[i], tn = tsf[i + 1];
        const float s2 = t * t, denom = s2 + 0.25f;
        StepC c;
        c.c_skip = 0.25f / denom;
        c.c_out  = t * 0.5f / sqrtf(denom);
        c.c_in   = 1.0f / sqrtf(denom);
        c.inv_t  = 1.0f / t;
        c.ce     = t / (0.04f + s2);
        const float dt = t - tn;
        c.two_dt = 2.f * dt;
        c.nc     = sqrtf(2.f * t * dt);
        c.pad    = 0.f;
        S.s[i] = c;
    }

    // K-split sized to remaining workspace
    int KS = 32;
    while (KS > 1 && head_bytes + (size_t)KS * NS * NCLS * 4 > ws_size) KS >>= 1;
    const int bkc = CHW / KS;

    sampler6_kernel<<<NS * 4, 448, 0, stream>>>(latents, S.t0, x, noise, W_net, b_net, XA, Amat, S, 0);
    sampler6_kernel<<<NS * 4, 448, 0, stream>>>(XA, 1.f, x, noise, W_net, b_net, XB, Amat, S, 6);
    sampler6_kernel<<<NS * 4, 448, 0, stream>>>(XB, 1.f, x, noise, W_net, b_net, XB, Amat, S, 12);
    gemm_kernel<<<16 * KS, 256, 0, stream>>>(Amat, W_cls, part, bkc);
    lse_kernel<<<(64 * NCLS + 255) / 256, 256, 0, stream>>>(part, b_cls, out, KS);
}